// Round 22
// baseline (77.092 us; speedup 1.0000x reference)
//
#include <hip/hip_runtime.h>
#include <math.h>

#define SS 4096
#define EE 1024
#define HH 16
#define DD 64
#define RMAX 128
#define NCOL 128
#define NTR  8
#define NRED 8
#define NPROJ 1536 // 2 rt * [4 kc * (3 m * 64 etiles16)]; e-split waves (r22)
#define NREDB 96   // d1b reduce blocks
#define NBG 64
#define NVS 16
#define NATT 256

// ---------------------------------------------------------------------------
// ws float offsets. LESSONS: (r9/r10) no 4KB-strided ws reads; (r3) no BULK
// global atomics; (r5/r7) no software grid barriers; (r13) no shallow-flight
// staging; (r14-r18) W-staging variants all ~40us; (r19) W-fetch halving -3.4us
// => not fetch-bound; (r20) k-stagger -4.9us => same-line contention real;
// (r21) 4-deep prefetch NULL => L1 MSHR-limited, not ILP-limited. (r22) fix:
// waves split E not K -> 4 waves share identical x addresses -> L1 hits for
// trailing waves; k-quadrant partials to ypart + d1b reduce (r17, verified).
//   meta   int[0..1]      (s0, L)
//   sumx   [EE]           @64
//   bgA    [EE]           @1088
//   betap  [HH][DD]       @2112   (atomic; zeroed by D1 block 0)
//   alphap [HH]           @3136
//   vsumh  [HH][DD]       @3200
//   partT  [EE][NCOL]     @8192
//   xT     [EE][RMAX]     @139264 (zero-padded rows r>=L)
//   qh     [HH][RMAX][DD] @270336 (rows L..127 zeroed by d1b)
//   kTh    [HH][DD][RMAX] @401408 (cols L..127 zeroed by d1b)
//   vh     [HH][RMAX][DD] @532480 (rows L..127 zeroed by d1b)
//   ypart  [4][3][EE][RMAX] @663552  (proj K-quadrant partials, 6 MB)
// ---------------------------------------------------------------------------
#define OFF_SUMX  64
#define OFF_BGA   1088
#define OFF_BETA  2112
#define OFF_ALPHA 3136
#define OFF_VSUM  3200
#define OFF_PART  8192
#define OFF_XT    (OFF_PART + EE * NCOL)
#define OFF_QH    (OFF_XT + EE * RMAX)
#define OFF_KTH   (OFF_QH + HH * RMAX * DD)
#define OFF_VH    (OFF_KTH + HH * DD * RMAX)
#define OFF_YP    (OFF_VH + HH * RMAX * DD)

__device__ __forceinline__ void seg_scan(const int* __restrict__ seg,
                                         const int* __restrict__ posp,
                                         int* sh, int& s0, int& L) {
    if (threadIdx.x == 0) { sh[0] = SS; sh[1] = -1; }
    __syncthreads();
    int sid = seg[posp[0]];
    int lmin = SS, lmax = -1;
    for (int i = threadIdx.x; i < SS; i += 256)
        if (seg[i] == sid) { lmin = min(lmin, i); lmax = max(lmax, i); }
#pragma unroll
    for (int off = 32; off; off >>= 1) {
        lmin = min(lmin, __shfl_xor(lmin, off));
        lmax = max(lmax, __shfl_xor(lmax, off));
    }
    if ((threadIdx.x & 63) == 0) { atomicMin(&sh[0], lmin); atomicMax(&sh[1], lmax); }
    __syncthreads();
    s0 = sh[0];
    L  = sh[1] - sh[0] + 1;
    if (L > RMAX) L = RMAX;
    if (L < 1)    L = 1;
}

// -------- D0: colsum -> partT (128 blk) || x-seg transpose -> xT (8 blk) ----
__global__ __launch_bounds__(256) void d0_kernel(
    const float* __restrict__ x, const int* __restrict__ seg,
    const int* __restrict__ posp, float* __restrict__ ws) {
    int bid = blockIdx.x, tid = threadIdx.x;
    if (bid < NCOL) {
        float* partT = ws + OFF_PART;
        int r0 = bid * (SS / NCOL);
        const float4* x4 = (const float4*)x;
        float4 a = make_float4(0.f, 0.f, 0.f, 0.f);
#pragma unroll 8
        for (int r = 0; r < SS / NCOL; ++r) {
            float4 v = x4[(size_t)(r0 + r) * 256 + tid];
            a.x += v.x; a.y += v.y; a.z += v.z; a.w += v.w;
        }
        partT[(size_t)(4 * tid + 0) * NCOL + bid] = a.x;
        partT[(size_t)(4 * tid + 1) * NCOL + bid] = a.y;
        partT[(size_t)(4 * tid + 2) * NCOL + bid] = a.z;
        partT[(size_t)(4 * tid + 3) * NCOL + bid] = a.w;
        return;
    }
    __shared__ float t[128 * 129];
    __shared__ int sh[2];
    int s0, L;
    seg_scan(seg, posp, sh, s0, L);
    int kb = bid - NCOL;
    if (kb == 0 && tid == 0) { ((int*)ws)[0] = s0; ((int*)ws)[1] = L; }
    int k0 = kb * 128;
    float* xT = ws + OFF_XT;
    for (int idx = tid; idx < 128 * 32; idx += 256) {
        int r = idx >> 5, c4 = idx & 31;
        float4 v = make_float4(0.f, 0.f, 0.f, 0.f);
        if (r < L) v = *(const float4*)(x + (size_t)(s0 + r) * EE + k0 + c4 * 4);
        t[r * 129 + c4 * 4 + 0] = v.x;
        t[r * 129 + c4 * 4 + 1] = v.y;
        t[r * 129 + c4 * 4 + 2] = v.z;
        t[r * 129 + c4 * 4 + 3] = v.w;
    }
    __syncthreads();
    for (int idx = tid; idx < 128 * 32; idx += 256) {
        int k = idx >> 5, r4 = idx & 31;
        float4 o;
        o.x = t[(r4 * 4 + 0) * 129 + k];
        o.y = t[(r4 * 4 + 1) * 129 + k];
        o.z = t[(r4 * 4 + 2) * 129 + k];
        o.w = t[(r4 * 4 + 3) * 129 + k];
        *(float4*)(xT + (size_t)(k0 + k) * RMAX + r4 * 4) = o;
    }
}

// -------- D1: sumx reduce + zero accum (8 blk) || QKV proj partials (1536) ---
// Block = (rt, kc, m, 16-e tile). The 4 waves split E (4 e each) and sweep the
// SAME 256-k quadrant with identical x addresses -> trailing waves L1-hit
// (MSHR relief). No cross-wave reduce; plain stores to ypart[kc].
__global__ __launch_bounds__(256) void d1_kernel(
    const float* __restrict__ Wq, const float* __restrict__ Wk,
    const float* __restrict__ Wv, float* __restrict__ ws) {
    int bid = blockIdx.x, tid = threadIdx.x;
    if (bid < NRED) {
        if (bid == 0) {   // zero betap+alphap atomic accumulators
            for (int i = tid; i < 1088; i += 256) (ws + OFF_BETA)[i] = 0.f;
        }
        const float* partT = ws + OFF_PART;
        int e  = bid * 128 + (tid >> 1);
        int c0 = (tid & 1) * 64;
        const float4* p4 = (const float4*)(partT + (size_t)e * NCOL + c0);
        float4 s4 = make_float4(0.f, 0.f, 0.f, 0.f);
#pragma unroll
        for (int i = 0; i < 16; ++i) {
            float4 v = p4[i];
            s4.x += v.x; s4.y += v.y; s4.z += v.z; s4.w += v.w;
        }
        float s = s4.x + s4.y + s4.z + s4.w;
        s += __shfl_xor(s, 1);
        if ((tid & 1) == 0) (ws + OFF_SUMX)[e] = s;
        return;
    }
    int L  = ((const int*)ws)[1];
    int Lp = (L + 63) & ~63;
    int pid = bid - NRED;         // 0..1535
    int rt  = (pid >= 768) ? 1 : 0;
    int rem = pid - rt * 768;     // 0..767 ; pair (p, p+768): same everything
    int kc  = rem & 3;            // k quadrant
    int rem2 = rem >> 2;          // 0..191
    int m   = rem2 / 64;          // 0..2
    int eb  = rem2 - m * 64;      // 0..63 (16-e tiles)
    int r0  = rt * 64;
    if (r0 >= Lp) return;
    const float* W = (m == 0) ? Wq : ((m == 1) ? Wk : Wv);
    int lane = tid & 63;
    int w4 = __builtin_amdgcn_readfirstlane(tid >> 6);   // wave id, uniform
    int e0 = eb * 16 + w4 * 4;    // wave's 4 e-columns
    const float* xcol = ws + OFF_XT + r0 + lane;
    // phase: same for all waves of the block AND for the (p,p+768) pair
    int kq = kc * 256;
    int ko = (rem2 & 31) * 8;     // intra-quadrant stagger, 8-aligned
    const float* wr0 = W + (size_t)e0 * EE + kq;         // wave-uniform
    float acc0 = 0.f, acc1 = 0.f, acc2 = 0.f, acc3 = 0.f;
    float xv0[8], xv1[8];
#pragma unroll
    for (int u = 0; u < 8; ++u) xv0[u] = xcol[(size_t)(kq + ko + u) * RMAX];
    for (int kk = 0; kk < 256; kk += 16) {
        int kA = (ko + kk) & 255;
        int kB = (ko + kk + 8) & 255;
        int kC = (ko + kk + 16) & 255;    // wraps on last iter (harmless L1 hit)
#pragma unroll
        for (int u = 0; u < 8; ++u)
            xv1[u] = xcol[(size_t)(kq + kB + u) * RMAX];
#pragma unroll
        for (int u = 0; u < 8; ++u) {
            float w0 = wr0[0 * EE + kA + u];
            float w1 = wr0[1 * EE + kA + u];
            float w2 = wr0[2 * EE + kA + u];
            float w3 = wr0[3 * EE + kA + u];
            acc0 += xv0[u] * w0; acc1 += xv0[u] * w1;
            acc2 += xv0[u] * w2; acc3 += xv0[u] * w3;
        }
#pragma unroll
        for (int u = 0; u < 8; ++u)
            xv0[u] = xcol[(size_t)(kq + kC + u) * RMAX];
#pragma unroll
        for (int u = 0; u < 8; ++u) {
            float w0 = wr0[0 * EE + kB + u];
            float w1 = wr0[1 * EE + kB + u];
            float w2 = wr0[2 * EE + kB + u];
            float w3 = wr0[3 * EE + kB + u];
            acc0 += xv1[u] * w0; acc1 += xv1[u] * w1;
            acc2 += xv1[u] * w2; acc3 += xv1[u] * w3;
        }
    }
    // plain coalesced partial stores: ypart[kc][m][e][r]
    float* yp = ws + OFF_YP + ((size_t)(kc * 3 + m) * EE) * RMAX;
    int rg = r0 + lane;
    yp[(size_t)(e0 + 0) * RMAX + rg] = acc0;
    yp[(size_t)(e0 + 1) * RMAX + rg] = acc1;
    yp[(size_t)(e0 + 2) * RMAX + rg] = acc2;
    yp[(size_t)(e0 + 3) * RMAX + rg] = acc3;
}

// -------- D1b: reduce ypart -> qh / kTh / vh (+bias, r<L gate). 96 blk -----
__global__ __launch_bounds__(256) void d1b_kernel(
    const float* __restrict__ bq, const float* __restrict__ bk,
    const float* __restrict__ bv, float* __restrict__ ws) {
    int bid = blockIdx.x, tid = threadIdx.x;
    int L = ((const int*)ws)[1];
    int Lp = (L + 63) & ~63;
    int m  = bid / 32;
    int et = bid % 32;
    const float* b = (m == 0) ? bq : ((m == 1) ? bk : bv);
    float* qh  = ws + OFF_QH;
    float* kTh = ws + OFF_KTH;
    float* vh  = ws + OFF_VH;
    const float* yp = ws + OFF_YP;
    int r4 = (tid & 31) * 4;          // float4 along r (covers 0..124)
    int ee = tid >> 5;                // 0..7
#pragma unroll
    for (int ep = 0; ep < 4; ++ep) {
        int e = et * 32 + ep * 8 + ee;
        size_t base = (size_t)e * RMAX + r4;
        float4 s = make_float4(0.f, 0.f, 0.f, 0.f);
        if (r4 < Lp) {                 // rt=1 partials absent when Lp==64
#pragma unroll
            for (int kc = 0; kc < 4; ++kc) {
                float4 v = *(const float4*)(yp + ((size_t)(kc * 3 + m) * EE) * RMAX + base);
                s.x += v.x; s.y += v.y; s.z += v.z; s.w += v.w;
            }
        }
        float bb = b[e];
        float o[4] = {s.x + bb, s.y + bb, s.z + bb, s.w + bb};
#pragma unroll
        for (int i = 0; i < 4; ++i) if (r4 + i >= L) o[i] = 0.f;
        int h = e >> 6, d = e & 63;
        if (m == 1) {
            *(float4*)(kTh + (size_t)(h * DD + d) * RMAX + r4) =
                make_float4(o[0], o[1], o[2], o[3]);
        } else {
            float* y = (m == 0) ? qh : vh;
#pragma unroll
            for (int i = 0; i < 4; ++i)
                y[((size_t)h * RMAX + r4 + i) * DD + d] = o[i];
        }
    }
}

// -------- D2: bgA (64) || vsumh (16) || attention, 1 wave per (r,h) (256) ----
__global__ __launch_bounds__(256) void d2_kernel(
    const float* __restrict__ Wv, const float* __restrict__ bv,
    float* __restrict__ ws) {
    __shared__ float qS[4 * 64];
    __shared__ float wS[4 * 128];
    __shared__ float vp_[4][64];
    const float* sumx = ws + OFF_SUMX;
    float* bgA    = ws + OFF_BGA;
    float* betap  = ws + OFF_BETA;
    float* alphap = ws + OFF_ALPHA;
    float* vsumh  = ws + OFF_VSUM;
    const float* qh  = ws + OFF_QH;
    const float* kTh = ws + OFF_KTH;
    const float* vh  = ws + OFF_VH;

    int bid = blockIdx.x, tid = threadIdx.x;
    int lane = tid & 63, wave = tid >> 6;
    int L  = ((const int*)ws)[1];
    int Lp = (L + 63) & ~63;

    if (bid < NBG) {
        int e = bid * 16 + (tid >> 4);
        int j = tid & 15;
        const float4* wr  = (const float4*)(Wv + (size_t)e * EE);
        const float4* sx4 = (const float4*)sumx;
        float p = 0.f;
#pragma unroll
        for (int jj = 0; jj < 16; ++jj) {
            float4 w = wr[jj * 16 + j], z = sx4[jj * 16 + j];
            p += w.x * z.x + w.y * z.y + w.z * z.z + w.w * z.w;
        }
        p += __shfl_xor(p, 8);
        p += __shfl_xor(p, 4);
        p += __shfl_xor(p, 2);
        p += __shfl_xor(p, 1);
        if (j == 0) bgA[e] = p + (float)SS * bv[e];
        return;
    }
    if (bid < NBG + NVS) {
        int h = bid - NBG;
        float s = 0.f;
        for (int t = wave; t < Lp; t += 4)
            s += vh[((size_t)h * RMAX + t) * DD + lane];
        vp_[wave][lane] = s;
        __syncthreads();
        if (wave == 0)
            vsumh[h * DD + lane] = vp_[0][lane] + vp_[1][lane]
                                 + vp_[2][lane] + vp_[3][lane];
        return;
    }

    int aid = bid - NBG - NVS;
    int gidbase = aid * 4 + wave;
    int pairs = L * HH;
    float* qSw = qS + wave * 64;
    float* wSw = wS + wave * 128;
    for (int wg = gidbase; wg < pairs; wg += NATT * 4) {
        int h = wg & (HH - 1);
        int r = wg >> 4;
        qSw[lane] = qh[((size_t)h * RMAX + r) * DD + lane];
        float s0 = 0.f, s1 = 0.f;
#pragma unroll
        for (int d = 0; d < 64; ++d) {
            float qd = qSw[d];
            const float* kr = kTh + (size_t)(h * DD + d) * RMAX;
            s0 += qd * kr[lane];
            s1 += qd * kr[64 + lane];
        }
        float v0 = (lane < L)      ? s0 : -3.0e38f;
        float v1 = (64 + lane < L) ? s1 : -3.0e38f;
        float m = fmaxf(0.f, fmaxf(v0, v1));
#pragma unroll
        for (int off = 32; off; off >>= 1) m = fmaxf(m, __shfl_xor(m, off));
        float w0 = (lane < L)      ? __expf(s0 - m) : 0.f;
        float w1 = (64 + lane < L) ? __expf(s1 - m) : 0.f;
        float Zl = w0 + w1;
#pragma unroll
        for (int off = 32; off; off >>= 1) Zl += __shfl_xor(Zl, off);
        float em = __expf(-m);
        float Z  = Zl + (float)(SS - L) * em;
        wSw[lane]      = w0;
        wSw[64 + lane] = w1;
        float acc = 0.f;
#pragma unroll 16
        for (int t = 0; t < Lp; ++t)
            acc += wSw[t] * vh[((size_t)h * RMAX + t) * DD + lane];
        float invZ = 1.0f / Z;
        atomicAdd(&betap[h * DD + lane], acc * invZ);
        if (lane == 0) atomicAdd(&alphap[h], em * invZ);
    }
}

// -------- D3: out[e] = bo[e] + Wo[e,:].(beta + alpha o (bgA - vsumh)) / L ----
__global__ __launch_bounds__(256) void d3_kernel(
    const float* __restrict__ Wo, const float* __restrict__ bo,
    const float* __restrict__ ws, float* __restrict__ out) {
    __shared__ float z[EE];
    int tid = threadIdx.x;
    int lane = tid & 63, wave = tid >> 6;
    int L = ((const int*)ws)[1];

    {
        int h = tid >> 4;
        float4 beta = ((const float4*)(ws + OFF_BETA))[tid];
        float  a    = (ws + OFF_ALPHA)[h];
        float4 g    = ((const float4*)(ws + OFF_BGA))[tid];
        float4 vs   = ((const float4*)(ws + OFF_VSUM))[tid];
        ((float4*)z)[tid] = make_float4(beta.x + a * (g.x - vs.x),
                                        beta.y + a * (g.y - vs.y),
                                        beta.z + a * (g.z - vs.z),
                                        beta.w + a * (g.w - vs.w));
    }
    __syncthreads();

    int e = blockIdx.x * 4 + wave;
    const float4* wr = (const float4*)(Wo + (size_t)e * EE);
    const float4* z4 = (const float4*)z;
    float p = 0.f;
#pragma unroll
    for (int it = 0; it < 4; ++it) {
        float4 w = wr[it * 64 + lane], zz = z4[it * 64 + lane];
        p += w.x * zz.x + w.y * zz.y + w.z * zz.z + w.w * zz.w;
    }
#pragma unroll
    for (int off = 32; off; off >>= 1) p += __shfl_xor(p, off);
    if (lane == 0) out[e] = bo[e] + p / (float)L;
}

extern "C" void kernel_launch(void* const* d_in, const int* in_sizes, int n_in,
                              void* d_out, int out_size, void* d_ws, size_t ws_size,
                              hipStream_t stream) {
    const float* x   = (const float*)d_in[0];
    const float* Wq  = (const float*)d_in[1];
    const float* bq  = (const float*)d_in[2];
    const float* Wk  = (const float*)d_in[3];
    const float* bk  = (const float*)d_in[4];
    const float* Wv  = (const float*)d_in[5];
    const float* bv  = (const float*)d_in[6];
    const float* Wo  = (const float*)d_in[7];
    const float* bo  = (const float*)d_in[8];
    const int*   seg = (const int*)d_in[9];
    const int*   pos = (const int*)d_in[10];
    float*       out = (float*)d_out;
    float*       ws  = (float*)d_ws;

    d0_kernel<<<NCOL + NTR, 256, 0, stream>>>(x, seg, pos, ws);
    d1_kernel<<<NRED + NPROJ, 256, 0, stream>>>(Wq, Wk, Wv, ws);
    d1b_kernel<<<NREDB, 256, 0, stream>>>(bq, bk, bv, ws);
    d2_kernel<<<NBG + NVS + NATT, 256, 0, stream>>>(Wv, bv, ws);
    d3_kernel<<<EE / 4, 256, 0, stream>>>(Wo, bo, ws, out);
}

// Round 23
// 71.124 us; speedup vs baseline: 1.0839x; 1.0839x over previous
//
#include <hip/hip_runtime.h>
#include <math.h>

#define SS 4096
#define EE 1024
#define HH 16
#define DD 64
#define RMAX 128
#define NCOL 128
#define NTR  8
#define NRED 8
#define NPROJ 768  // 4 kc * 3 m * 64 e-tiles(16e); both r-halves in-wave
#define NREDB 96   // d1b reduce blocks
#define NBG 64
#define NVS 16
#define NATT 256

// ---------------------------------------------------------------------------
// ws float offsets. LESSONS: (r9/r10) no 4KB-strided ws reads; (r3) no BULK
// global atomics; (r5/r7) no software grid barriers; (r13) no shallow-flight
// staging; (r19) not W-volume-bound; (r20) k-contention real; (r21) not
// ILP-depth-bound; (r22) e-split halved FETCH, time flat => W COLD-MISS
// CONCURRENCY is the limiter (scalar s_load queue / low-occupancy staging
// ~8 lines/CU => ~350GB/s => ~35us). (r23) fix: 16KB W stage via deep
// per-lane float4 streams at 3 blk/CU + FMA-bound inner loop (2 r-halves
// per LDS-broadcast W value).
//   meta   int[0..1]      (s0, L)
//   sumx   [EE]           @64
//   bgA    [EE]           @1088
//   betap  [HH][DD]       @2112   (atomic; zeroed by D1 block 0)
//   alphap [HH]           @3136
//   vsumh  [HH][DD]       @3200
//   partT  [EE][NCOL]     @8192
//   xT     [EE][RMAX]     @139264 (rows r>=L zeroed)
//   qh     [HH][RMAX][DD] @270336 (rows L..127 zeroed by d1b)
//   kTh    [HH][DD][RMAX] @401408 (cols L..127 zeroed by d1b)
//   vh     [HH][RMAX][DD] @532480 (rows L..127 zeroed by d1b)
//   ypart  [4][3][EE][RMAX] @663552  (proj K-quadrant partials, 6 MB)
// ---------------------------------------------------------------------------
#define OFF_SUMX  64
#define OFF_BGA   1088
#define OFF_BETA  2112
#define OFF_ALPHA 3136
#define OFF_VSUM  3200
#define OFF_PART  8192
#define OFF_XT    (OFF_PART + EE * NCOL)
#define OFF_QH    (OFF_XT + EE * RMAX)
#define OFF_KTH   (OFF_QH + HH * RMAX * DD)
#define OFF_VH    (OFF_KTH + HH * DD * RMAX)
#define OFF_YP    (OFF_VH + HH * RMAX * DD)

__device__ __forceinline__ void seg_scan(const int* __restrict__ seg,
                                         const int* __restrict__ posp,
                                         int* sh, int& s0, int& L) {
    if (threadIdx.x == 0) { sh[0] = SS; sh[1] = -1; }
    __syncthreads();
    int sid = seg[posp[0]];
    int lmin = SS, lmax = -1;
    for (int i = threadIdx.x; i < SS; i += 256)
        if (seg[i] == sid) { lmin = min(lmin, i); lmax = max(lmax, i); }
#pragma unroll
    for (int off = 32; off; off >>= 1) {
        lmin = min(lmin, __shfl_xor(lmin, off));
        lmax = max(lmax, __shfl_xor(lmax, off));
    }
    if ((threadIdx.x & 63) == 0) { atomicMin(&sh[0], lmin); atomicMax(&sh[1], lmax); }
    __syncthreads();
    s0 = sh[0];
    L  = sh[1] - sh[0] + 1;
    if (L > RMAX) L = RMAX;
    if (L < 1)    L = 1;
}

// -------- D0: colsum -> partT (128 blk) || x-seg transpose -> xT (8 blk) ----
__global__ __launch_bounds__(256) void d0_kernel(
    const float* __restrict__ x, const int* __restrict__ seg,
    const int* __restrict__ posp, float* __restrict__ ws) {
    int bid = blockIdx.x, tid = threadIdx.x;
    if (bid < NCOL) {
        float* partT = ws + OFF_PART;
        int r0 = bid * (SS / NCOL);
        const float4* x4 = (const float4*)x;
        float4 a = make_float4(0.f, 0.f, 0.f, 0.f);
#pragma unroll 8
        for (int r = 0; r < SS / NCOL; ++r) {
            float4 v = x4[(size_t)(r0 + r) * 256 + tid];
            a.x += v.x; a.y += v.y; a.z += v.z; a.w += v.w;
        }
        partT[(size_t)(4 * tid + 0) * NCOL + bid] = a.x;
        partT[(size_t)(4 * tid + 1) * NCOL + bid] = a.y;
        partT[(size_t)(4 * tid + 2) * NCOL + bid] = a.z;
        partT[(size_t)(4 * tid + 3) * NCOL + bid] = a.w;
        return;
    }
    __shared__ float t[128 * 129];
    __shared__ int sh[2];
    int s0, L;
    seg_scan(seg, posp, sh, s0, L);
    int kb = bid - NCOL;
    if (kb == 0 && tid == 0) { ((int*)ws)[0] = s0; ((int*)ws)[1] = L; }
    int k0 = kb * 128;
    float* xT = ws + OFF_XT;
    for (int idx = tid; idx < 128 * 32; idx += 256) {
        int r = idx >> 5, c4 = idx & 31;
        float4 v = make_float4(0.f, 0.f, 0.f, 0.f);
        if (r < L) v = *(const float4*)(x + (size_t)(s0 + r) * EE + k0 + c4 * 4);
        t[r * 129 + c4 * 4 + 0] = v.x;
        t[r * 129 + c4 * 4 + 1] = v.y;
        t[r * 129 + c4 * 4 + 2] = v.z;
        t[r * 129 + c4 * 4 + 3] = v.w;
    }
    __syncthreads();
    for (int idx = tid; idx < 128 * 32; idx += 256) {
        int k = idx >> 5, r4 = idx & 31;
        float4 o;
        o.x = t[(r4 * 4 + 0) * 129 + k];
        o.y = t[(r4 * 4 + 1) * 129 + k];
        o.z = t[(r4 * 4 + 2) * 129 + k];
        o.w = t[(r4 * 4 + 3) * 129 + k];
        *(float4*)(xT + (size_t)(k0 + k) * RMAX + r4 * 4) = o;
    }
}

// -------- D1: sumx reduce + zero accum (8 blk) || QKV proj partials (768) ----
// Block = (kc, m, 16-e tile). W slice [256k][16e] staged to 20KB LDS via
// 4 per-lane float4 streams (deep MLP). Wave = 4 e, 256 k, BOTH row-halves
// (lane & lane+64): per 8-k group FMA 128cy vs LDS 96cy => FMA-bound.
// Partials -> ypart[kc][m][e][r] (always fully written). No L dependence.
__global__ __launch_bounds__(256) void d1_kernel(
    const float* __restrict__ Wq, const float* __restrict__ Wk,
    const float* __restrict__ Wv, float* __restrict__ ws) {
    int bid = blockIdx.x, tid = threadIdx.x;
    if (bid < NRED) {
        if (bid == 0) {   // zero betap+alphap atomic accumulators
            for (int i = tid; i < 1088; i += 256) (ws + OFF_BETA)[i] = 0.f;
        }
        const float* partT = ws + OFF_PART;
        int e  = bid * 128 + (tid >> 1);
        int c0 = (tid & 1) * 64;
        const float4* p4 = (const float4*)(partT + (size_t)e * NCOL + c0);
        float4 s4 = make_float4(0.f, 0.f, 0.f, 0.f);
#pragma unroll
        for (int i = 0; i < 16; ++i) {
            float4 v = p4[i];
            s4.x += v.x; s4.y += v.y; s4.z += v.z; s4.w += v.w;
        }
        float s = s4.x + s4.y + s4.z + s4.w;
        s += __shfl_xor(s, 1);
        if ((tid & 1) == 0) (ws + OFF_SUMX)[e] = s;
        return;
    }
    __shared__ float ws2[256 * 20];   // [k][e] W quadrant slice, 20 KB
    int pid = bid - NRED;             // 0..767
    int kc  = pid & 3;                // k quadrant (inherent stagger)
    int rem = pid >> 2;               // 0..191
    int m   = rem / 64;               // 0..2
    int eb  = rem - m * 64;           // 0..63 (16-e tiles)
    const float* W = (m == 0) ? Wq : ((m == 1) ? Wk : Wv);
    int kq = kc * 256;
    int e0t = eb * 16;

    {   // stage W[e0t..+16)[kq..+256) -> ws2[k][e]; 4 coalesced float4/thread
#pragma unroll
        for (int p = 0; p < 4; ++p) {
            int idx = tid + p * 256;          // 0..1023
            int e = idx >> 6, k4 = idx & 63;
            float4 v = *(const float4*)(W + (size_t)(e0t + e) * EE + kq + k4 * 4);
            ws2[(k4 * 4 + 0) * 20 + e] = v.x;
            ws2[(k4 * 4 + 1) * 20 + e] = v.y;
            ws2[(k4 * 4 + 2) * 20 + e] = v.z;
            ws2[(k4 * 4 + 3) * 20 + e] = v.w;
        }
    }
    __syncthreads();

    int lane = tid & 63;
    int w4 = __builtin_amdgcn_readfirstlane(tid >> 6);   // wave id, uniform
    int eo = w4 * 4;                  // wave's 4 e (local)
    int ko = (eb & 31) * 8;           // intra-quadrant stagger, 8-aligned
    const float* xA = ws + OFF_XT + lane;        // half A: rows 0..63
    const float* xB = ws + OFF_XT + 64 + lane;   // half B: rows 64..127 (zeroed pad)
    float accA0 = 0.f, accA1 = 0.f, accA2 = 0.f, accA3 = 0.f;
    float accB0 = 0.f, accB1 = 0.f, accB2 = 0.f, accB3 = 0.f;
    float xa0[8], xb0[8], xa1[8], xb1[8];
#pragma unroll
    for (int u = 0; u < 8; ++u) {
        int k = kq + ((ko + u) & 255);
        xa0[u] = xA[(size_t)k * RMAX];
        xb0[u] = xB[(size_t)k * RMAX];
    }
    for (int kk = 0; kk < 256; kk += 16) {
        int g1 = ko + kk + 8, g2 = ko + kk + 16;
#pragma unroll
        for (int u = 0; u < 8; ++u) {
            int k = kq + ((g1 + u) & 255);
            xa1[u] = xA[(size_t)k * RMAX];
            xb1[u] = xB[(size_t)k * RMAX];
        }
#pragma unroll
        for (int u = 0; u < 8; ++u) {
            int kl = (ko + kk + u) & 255;
            float4 w = *(const float4*)&ws2[kl * 20 + eo];
            accA0 += w.x * xa0[u]; accA1 += w.y * xa0[u];
            accA2 += w.z * xa0[u]; accA3 += w.w * xa0[u];
            accB0 += w.x * xb0[u]; accB1 += w.y * xb0[u];
            accB2 += w.z * xb0[u]; accB3 += w.w * xb0[u];
        }
#pragma unroll
        for (int u = 0; u < 8; ++u) {
            int k = kq + ((g2 + u) & 255);    // wraps on last iter (L1 hits)
            xa0[u] = xA[(size_t)k * RMAX];
            xb0[u] = xB[(size_t)k * RMAX];
        }
#pragma unroll
        for (int u = 0; u < 8; ++u) {
            int kl = (g1 + u) & 255;
            float4 w = *(const float4*)&ws2[kl * 20 + eo];
            accA0 += w.x * xa1[u]; accA1 += w.y * xa1[u];
            accA2 += w.z * xa1[u]; accA3 += w.w * xa1[u];
            accB0 += w.x * xb1[u]; accB1 += w.y * xb1[u];
            accB2 += w.z * xb1[u]; accB3 += w.w * xb1[u];
        }
    }
    // plain coalesced partial stores: ypart[kc][m][e][r] (256B rows per e)
    float* yp = ws + OFF_YP + ((size_t)(kc * 3 + m) * EE) * RMAX;
    int e0 = e0t + eo;
    yp[(size_t)(e0 + 0) * RMAX + lane] = accA0;
    yp[(size_t)(e0 + 1) * RMAX + lane] = accA1;
    yp[(size_t)(e0 + 2) * RMAX + lane] = accA2;
    yp[(size_t)(e0 + 3) * RMAX + lane] = accA3;
    yp[(size_t)(e0 + 0) * RMAX + 64 + lane] = accB0;
    yp[(size_t)(e0 + 1) * RMAX + 64 + lane] = accB1;
    yp[(size_t)(e0 + 2) * RMAX + 64 + lane] = accB2;
    yp[(size_t)(e0 + 3) * RMAX + 64 + lane] = accB3;
}

// -------- D1b: reduce ypart -> qh / kTh / vh (+bias, r<L gate). 96 blk -----
__global__ __launch_bounds__(256) void d1b_kernel(
    const float* __restrict__ bq, const float* __restrict__ bk,
    const float* __restrict__ bv, float* __restrict__ ws) {
    int bid = blockIdx.x, tid = threadIdx.x;
    int L = ((const int*)ws)[1];
    int m  = bid / 32;
    int et = bid % 32;
    const float* b = (m == 0) ? bq : ((m == 1) ? bk : bv);
    float* qh  = ws + OFF_QH;
    float* kTh = ws + OFF_KTH;
    float* vh  = ws + OFF_VH;
    const float* yp = ws + OFF_YP;
    int r4 = (tid & 31) * 4;          // float4 along r
    int ee = tid >> 5;                // 0..7
#pragma unroll
    for (int ep = 0; ep < 4; ++ep) {
        int e = et * 32 + ep * 8 + ee;
        size_t base = (size_t)e * RMAX + r4;
        float4 s = make_float4(0.f, 0.f, 0.f, 0.f);
#pragma unroll
        for (int kc = 0; kc < 4; ++kc) {
            float4 v = *(const float4*)(yp + ((size_t)(kc * 3 + m) * EE) * RMAX + base);
            s.x += v.x; s.y += v.y; s.z += v.z; s.w += v.w;
        }
        float bb = b[e];
        float o[4] = {s.x + bb, s.y + bb, s.z + bb, s.w + bb};
#pragma unroll
        for (int i = 0; i < 4; ++i) if (r4 + i >= L) o[i] = 0.f;
        int h = e >> 6, d = e & 63;
        if (m == 1) {
            *(float4*)(kTh + (size_t)(h * DD + d) * RMAX + r4) =
                make_float4(o[0], o[1], o[2], o[3]);
        } else {
            float* y = (m == 0) ? qh : vh;
#pragma unroll
            for (int i = 0; i < 4; ++i)
                y[((size_t)h * RMAX + r4 + i) * DD + d] = o[i];
        }
    }
}

// -------- D2: bgA (64) || vsumh (16) || attention, 1 wave per (r,h) (256) ----
__global__ __launch_bounds__(256) void d2_kernel(
    const float* __restrict__ Wv, const float* __restrict__ bv,
    float* __restrict__ ws) {
    __shared__ float qS[4 * 64];
    __shared__ float wS[4 * 128];
    __shared__ float vp_[4][64];
    const float* sumx = ws + OFF_SUMX;
    float* bgA    = ws + OFF_BGA;
    float* betap  = ws + OFF_BETA;
    float* alphap = ws + OFF_ALPHA;
    float* vsumh  = ws + OFF_VSUM;
    const float* qh  = ws + OFF_QH;
    const float* kTh = ws + OFF_KTH;
    const float* vh  = ws + OFF_VH;

    int bid = blockIdx.x, tid = threadIdx.x;
    int lane = tid & 63, wave = tid >> 6;
    int L  = ((const int*)ws)[1];
    int Lp = (L + 63) & ~63;

    if (bid < NBG) {
        int e = bid * 16 + (tid >> 4);
        int j = tid & 15;
        const float4* wr  = (const float4*)(Wv + (size_t)e * EE);
        const float4* sx4 = (const float4*)sumx;
        float p = 0.f;
#pragma unroll
        for (int jj = 0; jj < 16; ++jj) {
            float4 w = wr[jj * 16 + j], z = sx4[jj * 16 + j];
            p += w.x * z.x + w.y * z.y + w.z * z.z + w.w * z.w;
        }
        p += __shfl_xor(p, 8);
        p += __shfl_xor(p, 4);
        p += __shfl_xor(p, 2);
        p += __shfl_xor(p, 1);
        if (j == 0) bgA[e] = p + (float)SS * bv[e];
        return;
    }
    if (bid < NBG + NVS) {
        int h = bid - NBG;
        float s = 0.f;
        for (int t = wave; t < Lp; t += 4)
            s += vh[((size_t)h * RMAX + t) * DD + lane];
        vp_[wave][lane] = s;
        __syncthreads();
        if (wave == 0)
            vsumh[h * DD + lane] = vp_[0][lane] + vp_[1][lane]
                                 + vp_[2][lane] + vp_[3][lane];
        return;
    }

    int aid = bid - NBG - NVS;
    int gidbase = aid * 4 + wave;
    int pairs = L * HH;
    float* qSw = qS + wave * 64;
    float* wSw = wS + wave * 128;
    for (int wg = gidbase; wg < pairs; wg += NATT * 4) {
        int h = wg & (HH - 1);
        int r = wg >> 4;
        qSw[lane] = qh[((size_t)h * RMAX + r) * DD + lane];
        float s0 = 0.f, s1 = 0.f;
#pragma unroll
        for (int d = 0; d < 64; ++d) {
            float qd = qSw[d];
            const float* kr = kTh + (size_t)(h * DD + d) * RMAX;
            s0 += qd * kr[lane];
            s1 += qd * kr[64 + lane];
        }
        float v0 = (lane < L)      ? s0 : -3.0e38f;
        float v1 = (64 + lane < L) ? s1 : -3.0e38f;
        float m = fmaxf(0.f, fmaxf(v0, v1));
#pragma unroll
        for (int off = 32; off; off >>= 1) m = fmaxf(m, __shfl_xor(m, off));
        float w0 = (lane < L)      ? __expf(s0 - m) : 0.f;
        float w1 = (64 + lane < L) ? __expf(s1 - m) : 0.f;
        float Zl = w0 + w1;
#pragma unroll
        for (int off = 32; off; off >>= 1) Zl += __shfl_xor(Zl, off);
        float em = __expf(-m);
        float Z  = Zl + (float)(SS - L) * em;
        wSw[lane]      = w0;
        wSw[64 + lane] = w1;
        float acc = 0.f;
#pragma unroll 16
        for (int t = 0; t < Lp; ++t)
            acc += wSw[t] * vh[((size_t)h * RMAX + t) * DD + lane];
        float invZ = 1.0f / Z;
        atomicAdd(&betap[h * DD + lane], acc * invZ);
        if (lane == 0) atomicAdd(&alphap[h], em * invZ);
    }
}

// -------- D3: out[e] = bo[e] + Wo[e,:].(beta + alpha o (bgA - vsumh)) / L ----
__global__ __launch_bounds__(256) void d3_kernel(
    const float* __restrict__ Wo, const float* __restrict__ bo,
    const float* __restrict__ ws, float* __restrict__ out) {
    __shared__ float z[EE];
    int tid = threadIdx.x;
    int lane = tid & 63, wave = tid >> 6;
    int L = ((const int*)ws)[1];

    {
        int h = tid >> 4;
        float4 beta = ((const float4*)(ws + OFF_BETA))[tid];
        float  a    = (ws + OFF_ALPHA)[h];
        float4 g    = ((const float4*)(ws + OFF_BGA))[tid];
        float4 vs   = ((const float4*)(ws + OFF_VSUM))[tid];
        ((float4*)z)[tid] = make_float4(beta.x + a * (g.x - vs.x),
                                        beta.y + a * (g.y - vs.y),
                                        beta.z + a * (g.z - vs.z),
                                        beta.w + a * (g.w - vs.w));
    }
    __syncthreads();

    int e = blockIdx.x * 4 + wave;
    const float4* wr = (const float4*)(Wo + (size_t)e * EE);
    const float4* z4 = (const float4*)z;
    float p = 0.f;
#pragma unroll
    for (int it = 0; it < 4; ++it) {
        float4 w = wr[it * 64 + lane], zz = z4[it * 64 + lane];
        p += w.x * zz.x + w.y * zz.y + w.z * zz.z + w.w * zz.w;
    }
#pragma unroll
    for (int off = 32; off; off >>= 1) p += __shfl_xor(p, off);
    if (lane == 0) out[e] = bo[e] + p / (float)L;
}

extern "C" void kernel_launch(void* const* d_in, const int* in_sizes, int n_in,
                              void* d_out, int out_size, void* d_ws, size_t ws_size,
                              hipStream_t stream) {
    const float* x   = (const float*)d_in[0];
    const float* Wq  = (const float*)d_in[1];
    const float* bq  = (const float*)d_in[2];
    const float* Wk  = (const float*)d_in[3];
    const float* bk  = (const float*)d_in[4];
    const float* Wv  = (const float*)d_in[5];
    const float* bv  = (const float*)d_in[6];
    const float* Wo  = (const float*)d_in[7];
    const float* bo  = (const float*)d_in[8];
    const int*   seg = (const int*)d_in[9];
    const int*   pos = (const int*)d_in[10];
    float*       out = (float*)d_out;
    float*       ws  = (float*)d_ws;

    d0_kernel<<<NCOL + NTR, 256, 0, stream>>>(x, seg, pos, ws);
    d1_kernel<<<NRED + NPROJ, 256, 0, stream>>>(Wq, Wk, Wv, ws);
    d1b_kernel<<<NREDB, 256, 0, stream>>>(bq, bk, bv, ws);
    d2_kernel<<<NBG + NVS + NATT, 256, 0, stream>>>(Wv, bv, ws);
    d3_kernel<<<EE / 4, 256, 0, stream>>>(Wo, bo, ws, out);
}